// Round 8
// baseline (2047.467 us; speedup 1.0000x reference)
//
#include <hip/hip_runtime.h>
#include <math.h>

// TransformerVAE forward — round 12.
// GEMM (split-phase + XCD swizzle) and attn3 kept VERBATIM from round 11
// (best total, 2028 µs; GEMM schedule space declared exhausted: 7 variants
// all 455-535 TF). This round removes ancillary structural waste:
//  (a) wtcast: ONE exact-grid dispatch per encoder/decoder (6144 blocks, all
//      working) replacing 8 dispatches of 24576 blocks at ~3% utilization.
//      Workspace-safe fallback to the per-layer path if the 12 MB batch
//      buffer doesn't fit.
//  (b) cast_ln_k / stats_k: wave-per-row rewrite — 4 rows/block, __shfl_xor
//      butterfly reduce, no LDS, no __syncthreads, float4x2 loads, single
//      16-B bf16 store. 32768 -> 8192 blocks.
//  (c) pool_ln_k: grid (64,8) = 512 blocks (was 64 -> 25% CU coverage).
// B=64, S=512, INP=64, D=512, H=8, dk=64, L=2, DFF=2048, LAT=128, topk=6.

#define SQRT_D 22.62741699796952f
#define PE_C   0.017988946039015984f   // ln(10000)/512

typedef short frag8 __attribute__((ext_vector_type(8)));   // 8 bf16
typedef float accf4 __attribute__((ext_vector_type(4)));   // 4 fp32 acc

#define GLL16(g, l) __builtin_amdgcn_global_load_lds( \
    (const __attribute__((address_space(1))) void*)(g), \
    (__attribute__((address_space(3))) void*)(l), 16, 0, 0)

__device__ __forceinline__ float bf2f(unsigned short u) {
    union { unsigned i; float f; } v; v.i = ((unsigned)u) << 16; return v.f;
}
__device__ __forceinline__ unsigned short f2bf(float f) {   // RNE
    union { float f; unsigned i; } v; v.f = f;
    unsigned r = v.i + 0x7fff + ((v.i >> 16) & 1);
    return (unsigned short)(r >> 16);
}
__device__ __forceinline__ float pe_val(int s, int d) {
    float div = expf(-(float)(d & ~1) * PE_C);
    float ang = (float)s * div;
    return (d & 1) ? cosf(ang) : sinf(ang);
}
__device__ __forceinline__ float gelu_exact(float x) {
    return 0.5f * x * (1.0f + erff(x * 0.7071067811865476f));
}
// Abramowitz-Stegun 7.1.26 erf, |err| < 1.5e-7 (≪ bf16 output quantum).
__device__ __forceinline__ float gelu_fast(float x) {
    float xs = x * 0.7071067811865476f;
    float ax = fabsf(xs);
    float t  = 1.0f / (1.0f + 0.3275911f * ax);
    float p  = t * (0.254829592f + t * (-0.284496736f + t * (1.421413741f +
               t * (-1.453152027f + t * 1.061405429f))));
    float er = 1.0f - p * __expf(-ax * ax);
    er = (xs < 0.0f) ? -er : er;
    return 0.5f * x * (1.0f + er);
}

__device__ __forceinline__ void phase_bar() {
    __builtin_amdgcn_sched_barrier(0);
    __builtin_amdgcn_s_barrier();
    __builtin_amdgcn_sched_barrier(0);
}

// ---------------------------------------------------------------- PE table
__global__ __launch_bounds__(256) void pe_k(float* __restrict__ pe)
{
    const int s = blockIdx.x;
    const int d = threadIdx.x;
    pe[s * 512 + d]       = pe_val(s, d);
    pe[s * 512 + d + 256] = pe_val(s, d + 256);
}

// ---------------------------------------------------------------- embed (enc)
__global__ __launch_bounds__(256) void embed_gemm_k(
    const float* __restrict__ x, const float* __restrict__ W,
    const float* __restrict__ bias, const float* __restrict__ pe,
    float* __restrict__ h)
{
    __shared__ float As[64][68];   // As[kk][b]
    __shared__ float Ws[64][68];   // Ws[kk][c]
    const int s = blockIdx.y;
    const int col0 = blockIdx.x * 64;
    const int tid = threadIdx.x;
#pragma unroll
    for (int i = 0; i < 16; i++) {
        int idx = i * 256 + tid;
        int r = idx >> 6, kk = idx & 63;
        As[kk][r] = x[((size_t)r * 512 + s) * 64 + kk];       // r = b
        Ws[r][kk] = W[(size_t)r * 512 + col0 + kk];           // r = k, kk = c
    }
    __syncthreads();
    const int tm = (tid >> 4) << 2;
    const int tn = (tid & 15) << 2;
    float acc[4][4] = {};
#pragma unroll 8
    for (int kk = 0; kk < 64; kk++) {
        float4 a4 = *reinterpret_cast<const float4*>(&As[kk][tm]);
        float4 b4 = *reinterpret_cast<const float4*>(&Ws[kk][tn]);
        const float a[4] = {a4.x, a4.y, a4.z, a4.w};
        const float b[4] = {b4.x, b4.y, b4.z, b4.w};
#pragma unroll
        for (int i = 0; i < 4; i++)
#pragma unroll
            for (int j = 0; j < 4; j++)
                acc[i][j] += a[i] * b[j];
    }
    const int c = col0 + tn;
    float4 bi = *reinterpret_cast<const float4*>(&bias[c]);
    float4 pp = *reinterpret_cast<const float4*>(&pe[s * 512 + c]);
#pragma unroll
    for (int i = 0; i < 4; i++) {
        size_t row = ((size_t)s * 64 + tm + i) * 512;
        float4 o;
        o.x = (acc[i][0] + bi.x) * SQRT_D + pp.x;
        o.y = (acc[i][1] + bi.y) * SQRT_D + pp.y;
        o.z = (acc[i][2] + bi.z) * SQRT_D + pp.z;
        o.w = (acc[i][3] + bi.w) * SQRT_D + pp.w;
        *reinterpret_cast<float4*>(&h[row + c]) = o;
    }
}

// ---------------------------------------------------------------- embed (dec)
__global__ __launch_bounds__(256) void dec_embed_k(
    const float* __restrict__ zemb, const float* __restrict__ pe,
    float* __restrict__ h)
{
    const int i4 = (blockIdx.x * 256 + threadIdx.x) * 4;   // grid 16384
    const int d = i4 & 511;
    const int t = i4 >> 9;
    const int s = t >> 6, b = t & 63;
    float4 z = *reinterpret_cast<const float4*>(&zemb[b * 512 + d]);
    float4 p = *reinterpret_cast<const float4*>(&pe[s * 512 + d]);
    float4 o;
    o.x = z.x * SQRT_D + p.x;
    o.y = z.y * SQRT_D + p.y;
    o.z = z.z * SQRT_D + p.z;
    o.w = z.w * SQRT_D + p.w;
    *reinterpret_cast<float4*>(&h[i4]) = o;
}

// ------------------------------------------------- LN stats (wave-per-row)
__global__ __launch_bounds__(256) void stats_k(
    const float* __restrict__ x, float* __restrict__ st)
{
    const int wave = threadIdx.x >> 6, lane = threadIdx.x & 63;
    const int row = blockIdx.x * 4 + wave;
    const float* xr = x + (size_t)row * 512 + lane * 8;
    float4 a = *reinterpret_cast<const float4*>(xr);
    float4 c = *reinterpret_cast<const float4*>(xr + 4);
    float s = a.x + a.y + a.z + a.w + c.x + c.y + c.z + c.w;
#pragma unroll
    for (int off = 32; off > 0; off >>= 1) s += __shfl_xor(s, off, 64);
    const float m = s * (1.f / 512.f);
    float d0 = a.x - m, d1 = a.y - m, d2 = a.z - m, d3 = a.w - m;
    float d4 = c.x - m, d5 = c.y - m, d6 = c.z - m, d7 = c.w - m;
    float s2 = d0*d0 + d1*d1 + d2*d2 + d3*d3 + d4*d4 + d5*d5 + d6*d6 + d7*d7;
#pragma unroll
    for (int off = 32; off > 0; off >>= 1) s2 += __shfl_xor(s2, off, 64);
    if (lane == 0) {
        st[row * 2]     = m;
        st[row * 2 + 1] = rsqrtf(s2 * (1.f / 512.f) + 1e-5f);
    }
}

// ------------------------------------------------- LN->bf16 (wave-per-row)
__global__ __launch_bounds__(256) void cast_ln_k(
    const float* __restrict__ x, const float* __restrict__ g,
    const float* __restrict__ b, unsigned short* __restrict__ y)
{
    const int wave = threadIdx.x >> 6, lane = threadIdx.x & 63;
    const int row = blockIdx.x * 4 + wave;
    const float* xr = x + (size_t)row * 512 + lane * 8;
    float4 a = *reinterpret_cast<const float4*>(xr);
    float4 c = *reinterpret_cast<const float4*>(xr + 4);
    float s = a.x + a.y + a.z + a.w + c.x + c.y + c.z + c.w;
#pragma unroll
    for (int off = 32; off > 0; off >>= 1) s += __shfl_xor(s, off, 64);
    const float m = s * (1.f / 512.f);
    float d0 = a.x - m, d1 = a.y - m, d2 = a.z - m, d3 = a.w - m;
    float d4 = c.x - m, d5 = c.y - m, d6 = c.z - m, d7 = c.w - m;
    float s2 = d0*d0 + d1*d1 + d2*d2 + d3*d3 + d4*d4 + d5*d5 + d6*d6 + d7*d7;
#pragma unroll
    for (int off = 32; off > 0; off >>= 1) s2 += __shfl_xor(s2, off, 64);
    const float rstd = rsqrtf(s2 * (1.f / 512.f) + 1e-5f);
    float4 g0 = *reinterpret_cast<const float4*>(&g[lane * 8]);
    float4 g1 = *reinterpret_cast<const float4*>(&g[lane * 8 + 4]);
    float4 b0 = *reinterpret_cast<const float4*>(&b[lane * 8]);
    float4 b1 = *reinterpret_cast<const float4*>(&b[lane * 8 + 4]);
    frag8 o;
    o[0] = (short)f2bf(d0 * rstd * g0.x + b0.x);
    o[1] = (short)f2bf(d1 * rstd * g0.y + b0.y);
    o[2] = (short)f2bf(d2 * rstd * g0.z + b0.z);
    o[3] = (short)f2bf(d3 * rstd * g0.w + b0.w);
    o[4] = (short)f2bf(d4 * rstd * g1.x + b1.x);
    o[5] = (short)f2bf(d5 * rstd * g1.y + b1.y);
    o[6] = (short)f2bf(d6 * rstd * g1.z + b1.z);
    o[7] = (short)f2bf(d7 * rstd * g1.w + b1.w);
    *reinterpret_cast<frag8*>(&y[(size_t)row * 512 + lane * 8]) = o;
}

// ------------------------------------------------------- weight transpose+cast
struct WTDesc { const float* src; unsigned short* dst; int Kd; int Nd; };

__global__ __launch_bounds__(256) void wtcast6_k(
    WTDesc d0, WTDesc d1, WTDesc d2, WTDesc d3, WTDesc d4, WTDesc d5)
{
    WTDesc d;
    switch (blockIdx.z) {
        case 0: d = d0; break; case 1: d = d1; break; case 2: d = d2; break;
        case 3: d = d3; break; case 4: d = d4; break; default: d = d5; break;
    }
    const int n0 = blockIdx.x * 32, k0 = blockIdx.y * 32;
    if (n0 >= d.Nd || k0 >= d.Kd) return;
    __shared__ float t[32][33];
    const int tx = threadIdx.x & 31, ty = threadIdx.x >> 5;   // ty 0..7
#pragma unroll
    for (int i = 0; i < 32; i += 8)
        t[ty + i][tx] = d.src[(size_t)(k0 + ty + i) * d.Nd + (n0 + tx)];
    __syncthreads();
#pragma unroll
    for (int i = 0; i < 32; i += 8)
        d.dst[(size_t)(n0 + ty + i) * d.Kd + (k0 + tx)] = f2bf(t[tx][ty + i]);
}

// ------------------------------------ batched 2-layer weight transpose+cast
// Exact grid: 2 layers x 3072 tiles = 6144 blocks, all working.
// Per-layer dst layout (shorts): wq 0, wk 262144, wv 524288, wo 786432,
// f1 1048576, f2 2097152; layer stride 3145728.
struct WTB { const float* src[12]; };   // [layer*6 + {wq,wk,wv,wo,f1,f2}]

__global__ __launch_bounds__(256) void wtcast_b_k(
    WTB w, unsigned short* __restrict__ dstbase)
{
    const int id = blockIdx.x;
    const int layer = id / 3072, r = id - layer * 3072;
    int di, t;
    if (r < 1024)      { di = r >> 8; t = r & 255; }
    else if (r < 2048) { di = 4; t = r - 1024; }
    else               { di = 5; t = r - 2048; }
    const float* src = w.src[layer * 6 + di];
    int Kd, Nd, n0, k0; size_t doff;
    if (di == 4)      { Kd = 512;  Nd = 2048; n0 = (t & 63) * 32; k0 = (t >> 6) * 32; doff = 1048576; }
    else if (di == 5) { Kd = 2048; Nd = 512;  n0 = (t & 15) * 32; k0 = (t >> 4) * 32; doff = 2097152; }
    else              { Kd = 512;  Nd = 512;  n0 = (t & 15) * 32; k0 = (t >> 4) * 32; doff = (size_t)di * 262144; }
    unsigned short* dst = dstbase + (size_t)layer * 3145728 + doff;
    __shared__ float tt[32][33];
    const int tx = threadIdx.x & 31, ty = threadIdx.x >> 5;
#pragma unroll
    for (int i = 0; i < 32; i += 8)
        tt[ty + i][tx] = src[(size_t)(k0 + ty + i) * Nd + (n0 + tx)];
    __syncthreads();
#pragma unroll
    for (int i = 0; i < 32; i += 8)
        dst[(size_t)(n0 + ty + i) * Kd + (k0 + tx)] = f2bf(tt[tx][ty + i]);
}

// ------------------------------------------------ MFMA GEMM 128x128, 4-wave
// Round-11 kernel verbatim: split 4-barrier schedule + bijective XCD swizzle.
template<int ACT, int OUTBF, int RES, int BIAS>
__global__ __launch_bounds__(256, 2) void mgemm128_k(
    const unsigned short* __restrict__ A, int lda,
    const unsigned short* __restrict__ Bt, int ldb,
    const float* __restrict__ bias,
    const float* res, float* Cf, unsigned short* Cb, int ldc, int K)
{
    __shared__ unsigned short sm[32768];   // 64 KiB: 2 buf x (A 16K + B 16K)
    const int tid = threadIdx.x;
    const int wave = tid >> 6, lane = tid & 63;

    int bx = blockIdx.x, by = blockIdx.y;
    if (gridDim.x == 256) {                 // bijective XCD swizzle
        const int id = blockIdx.x + (blockIdx.y << 8);
        const int span = gridDim.y << 4;    // 16*C
        const int xcd = id & 7;
        const int q = id >> 3;              // [0, 32*C)
        const int hb = q / span;            // 0 or 1 (16-row half-band)
        const int r2 = q - hb * span;
        bx = (xcd << 5) + (hb << 4) + (r2 & 15);
        by = r2 >> 4;
    }
    const int row0 = bx * 128;
    const int col0 = by * 128;

    const int wr = wave >> 1, wc = wave & 1;           // 2 x 2 wave grid
    const int wrbase = wr * 64, wcbase = wc * 64;
    const int frow = lane & 15;
    const int fcol = (lane >> 4) * 8;                  // elem col base
    const int fxorE = (lane & 7) << 3;                 // elem xor (row&7)<<3
    const int ccol = ((lane & 7) ^ (lane >> 3)) * 8;   // inverse-swizzled col

    const int NT = K >> 6;

    auto stageA = [&](int buf, int k0t) {
#pragma unroll
        for (int i = 0; i < 4; i++) {
            int chunk = wave * 4 + i;                  // 16 chunks x 8 rows
            GLL16(A + (size_t)(row0 + chunk * 8 + (lane >> 3)) * lda + k0t + ccol,
                  &sm[buf * 16384 + chunk * 512]);
        }
    };
    auto stageB = [&](int buf, int k0t) {
#pragma unroll
        for (int i = 0; i < 4; i++) {
            int chunk = wave * 4 + i;
            GLL16(Bt + (size_t)(col0 + chunk * 8 + (lane >> 3)) * ldb + k0t + ccol,
                  &sm[buf * 16384 + 8192 + chunk * 512]);
        }
    };

    accf4 acc[4][4] = {};
    frag8 af0[4], af1[4], bfr[4][2];

    // ---- prologue: stage tiles 0,1; wait tile 0 (tile 1's 8 stay in flight)
    stageA(0, 0); stageB(0, 0);
    if (NT > 1) { stageA(1, 64); stageB(1, 64); }
    if (NT > 1) asm volatile("s_waitcnt vmcnt(8)" ::: "memory");
    else        asm volatile("s_waitcnt vmcnt(0)" ::: "memory");
    phase_bar();

    for (int t = 0; t < NT; ++t) {
        const int ab = (t & 1) * 16384;
        const int bb = ab + 8192;
        const bool pf = (t + 2) < NT;
        const int kpf = (t + 2) << 6;

        // ---- ph0 read: A-k0 (4) + B all (8)
#pragma unroll
        for (int mi = 0; mi < 4; mi++)
            af0[mi] = *(const frag8*)&sm[ab + (wrbase + mi * 16 + frow) * 64 + (fcol ^ fxorE)];
#pragma unroll
        for (int nj = 0; nj < 4; nj++)
#pragma unroll
            for (int ks = 0; ks < 2; ks++)
                bfr[nj][ks] = *(const frag8*)&sm[bb + (wcbase + nj * 16 + frow) * 64 + ((ks * 32 + fcol) ^ fxorE)];
        phase_bar();
        // ---- ph0 mfma: ks=0 quadrants (16 independent MFMAs)
        __builtin_amdgcn_s_setprio(1);
#pragma unroll
        for (int mi = 0; mi < 4; mi++)
#pragma unroll
            for (int nj = 0; nj < 4; nj++)
                acc[mi][nj] = __builtin_amdgcn_mfma_f32_16x16x32_bf16(
                    bfr[nj][0], af0[mi], acc[mi][nj], 0, 0, 0);
        __builtin_amdgcn_s_setprio(0);
        phase_bar();

        // ---- ph1 read: A-k1 (4); restage B(t+2) (B reads ended last phase)
#pragma unroll
        for (int mi = 0; mi < 4; mi++)
            af1[mi] = *(const frag8*)&sm[ab + (wrbase + mi * 16 + frow) * 64 + ((32 + fcol) ^ fxorE)];
        if (pf) stageB(t & 1, kpf);
        phase_bar();
        // ---- ph1 mfma: ks=1; restage A(t+2) after the MFMA cluster
        __builtin_amdgcn_s_setprio(1);
#pragma unroll
        for (int mi = 0; mi < 4; mi++)
#pragma unroll
            for (int nj = 0; nj < 4; nj++)
                acc[mi][nj] = __builtin_amdgcn_mfma_f32_16x16x32_bf16(
                    bfr[nj][1], af1[mi], acc[mi][nj], 0, 0, 0);
        __builtin_amdgcn_s_setprio(0);
        if (pf) stageA(t & 1, kpf);
        // gate: allow only t+2's 8 loads outstanding -> t+1 fully landed
        if (pf) asm volatile("s_waitcnt vmcnt(8)" ::: "memory");
        else    asm volatile("s_waitcnt vmcnt(0)" ::: "memory");
        phase_bar();
    }

    // ---- epilogue (swapped C/D map: row = lane&15, col = (lane>>4)*4 + reg)
    const int lrow = lane & 15;
    const int lcol = (lane >> 4) * 4;
#pragma unroll
    for (int mi = 0; mi < 4; mi++) {
        const int r = row0 + wrbase + mi * 16 + lrow;
#pragma unroll
        for (int nj = 0; nj < 4; nj++) {
            const int c = col0 + wcbase + nj * 16 + lcol;
            float4 v = make_float4(acc[mi][nj][0], acc[mi][nj][1],
                                   acc[mi][nj][2], acc[mi][nj][3]);
            if (BIAS) {
                float4 bi = *reinterpret_cast<const float4*>(&bias[c]);
                v.x += bi.x; v.y += bi.y; v.z += bi.z; v.w += bi.w;
            }
            if (ACT) {
                v.x = gelu_fast(v.x); v.y = gelu_fast(v.y);
                v.z = gelu_fast(v.z); v.w = gelu_fast(v.w);
            }
            if (RES) {
                float4 rr = *reinterpret_cast<const float4*>(&res[(size_t)r * ldc + c]);
                v.x += rr.x; v.y += rr.y; v.z += rr.z; v.w += rr.w;
            }
            if (OUTBF) {
                ushort4 o;
                o.x = f2bf(v.x); o.y = f2bf(v.y); o.z = f2bf(v.z); o.w = f2bf(v.w);
                *reinterpret_cast<ushort4*>(&Cb[(size_t)r * ldc + c]) = o;
            } else {
                *reinterpret_cast<float4*>(&Cf[(size_t)r * ldc + c]) = v;
            }
        }
    }
}

// ---------------------------------------------------------------- attention
// MFMA attention: QK^T and PV on matrix cores, top-6 + softmax on VALU.
__global__ __launch_bounds__(256) void attn3_k(
    const unsigned short* __restrict__ qkv, unsigned short* __restrict__ ctx)
{
    __shared__ unsigned short QL[4096];   // Q (swizzled); later P (bf16)
    __shared__ unsigned short KL[4096];   // K (swizzled); later top-k cand (f32)
    __shared__ unsigned short VT[4096];   // V^T (swizzled): VT[j][c] = V[c][j]
    __shared__ float ScT[64][68];         // S^T[c][r]; [r][64]=thr, [r][65]=max
    __shared__ float dsums[64][4];
    __shared__ float rds[64];
    const int blk = blockIdx.x;
    const int sl = blk >> 3, hh = blk & 7;
    const int tid = threadIdx.x;
    const int wave = tid >> 6, lane = tid & 63;
    const size_t qbase = (size_t)sl * 64 * 1536 + (size_t)hh * 64;

    {
        const int r = tid >> 2;              // 0..63
        const int dg = (tid & 3) << 4;       // 0,16,32,48
        const int x = (r & 7) << 3;
        const unsigned short* gp = qkv + qbase + (size_t)r * 1536 + dg;
        frag8 q0 = *(const frag8*)(gp);
        frag8 q1 = *(const frag8*)(gp + 8);
        frag8 k0 = *(const frag8*)(gp + 512);
        frag8 k1 = *(const frag8*)(gp + 520);
        frag8 v0 = *(const frag8*)(gp + 1024);
        frag8 v1 = *(const frag8*)(gp + 1032);
        *(frag8*)&QL[r * 64 + (dg ^ x)]       = q0;
        *(frag8*)&QL[r * 64 + ((dg + 8) ^ x)] = q1;
        *(frag8*)&KL[r * 64 + (dg ^ x)]       = k0;
        *(frag8*)&KL[r * 64 + ((dg + 8) ^ x)] = k1;
#pragma unroll
        for (int i = 0; i < 16; i++) {
            int ii = (i + r) & 15;
            int j = dg + ii;
            unsigned short e = (unsigned short)(ii < 8 ? v0[ii] : v1[ii - 8]);
            VT[j * 64 + (r ^ ((j & 7) << 3))] = e;
        }
    }
    __syncthreads();

    const int frow = lane & 15;
    const int fcol8 = (lane >> 4) * 8;
    const int fx = (lane & 7) << 3;

    {   // QK^T
        const int c0 = wave * 16;
        accf4 sacc[4] = {};
#pragma unroll
        for (int ks = 0; ks < 2; ks++) {
            frag8 kf = *(const frag8*)&KL[(c0 + frow) * 64 + ((ks * 32 + fcol8) ^ fx)];
#pragma unroll
            for (int rt = 0; rt < 4; rt++) {
                frag8 qf = *(const frag8*)&QL[(rt * 16 + frow) * 64 + ((ks * 32 + fcol8) ^ fx)];
                sacc[rt] = __builtin_amdgcn_mfma_f32_16x16x32_bf16(
                    qf, kf, sacc[rt], 0, 0, 0);
            }
        }
        const int cc = c0 + frow;
        const int rb = (lane >> 4) * 4;
#pragma unroll
        for (int rt = 0; rt < 4; rt++) {
            float4 s4;
            s4.x = sacc[rt][0] * 0.125f; s4.y = sacc[rt][1] * 0.125f;
            s4.z = sacc[rt][2] * 0.125f; s4.w = sacc[rt][3] * 0.125f;
            *(float4*)&ScT[cc][rt * 16 + rb] = s4;
        }
    }
    __syncthreads();

    const int row = tid & 63, seg = tid >> 6;
    float* candp = (float*)&KL[0];
    {
        float top[6];
#pragma unroll
        for (int i = 0; i < 6; i++) top[i] = -3.4e38f;
#pragma unroll
        for (int c = seg * 16; c < seg * 16 + 16; c++) {
            float vv = ScT[c][row];
            if (vv > top[5]) {
                top[5] = vv;
#pragma unroll
                for (int i = 5; i > 0; i--)
                    if (top[i] > top[i - 1]) { float t = top[i]; top[i] = top[i - 1]; top[i - 1] = t; }
            }
        }
#pragma unroll
        for (int i = 0; i < 6; i++) candp[row * 24 + seg * 6 + i] = top[i];
    }
    __syncthreads();
    if (seg == 0) {
        float t6[6];
#pragma unroll
        for (int i = 0; i < 6; i++) t6[i] = -3.4e38f;
#pragma unroll
        for (int j = 0; j < 24; j++) {
            float vv = candp[row * 24 + j];
            if (vv > t6[5]) {
                t6[5] = vv;
#pragma unroll
                for (int i = 5; i > 0; i--)
                    if (t6[i] > t6[i - 1]) { float t = t6[i]; t6[i] = t6[i - 1]; t6[i - 1] = t; }
            }
        }
        ScT[row][64] = t6[5];
        ScT[row][65] = t6[0];
    }
    __syncthreads();
    {
        const float thresh = ScT[row][64], mx = ScT[row][65];
        const int xr = (row & 7) << 3;
        float dsum = 0.f;
#pragma unroll
        for (int c = seg * 16; c < seg * 16 + 16; c++) {
            float vv = ScT[c][row];
            float w = (vv >= thresh) ? expf(vv - mx) : 0.f;
            unsigned short wb = f2bf(w);
            dsum += bf2f(wb);
            QL[row * 64 + (c ^ xr)] = wb;
        }
        dsums[row][seg] = dsum;
    }
    __syncthreads();
    if (tid < 64)
        rds[tid] = 1.f / (dsums[tid][0] + dsums[tid][1] + dsums[tid][2] + dsums[tid][3]);
    __syncthreads();

    {   // PV
        const int r0 = wave * 16;
        accf4 pacc[4] = {};
#pragma unroll
        for (int ks = 0; ks < 2; ks++) {
            frag8 pf = *(const frag8*)&QL[(r0 + frow) * 64 + ((ks * 32 + fcol8) ^ fx)];
#pragma unroll
            for (int jt = 0; jt < 4; jt++) {
                frag8 vf = *(const frag8*)&VT[(jt * 16 + frow) * 64 + ((ks * 32 + fcol8) ^ fx)];
                pacc[jt] = __builtin_amdgcn_mfma_f32_16x16x32_bf16(
                    vf, pf, pacc[jt], 0, 0, 0);
            }
        }
        const int rr = r0 + frow;
        const int jb = (lane >> 4) * 4;
        const float sc = rds[rr];
#pragma unroll
        for (int jt = 0; jt < 4; jt++) {
            ushort4 o;
            o.x = f2bf(pacc[jt][0] * sc); o.y = f2bf(pacc[jt][1] * sc);
            o.z = f2bf(pacc[jt][2] * sc); o.w = f2bf(pacc[jt][3] * sc);
            *reinterpret_cast<ushort4*>(
                &ctx[(size_t)(sl * 64 + rr) * 512 + hh * 64 + jt * 16 + jb]) = o;
        }
    }
}

// ---------------------------------------------------------- fp32 GEMM (small)
template<int ACT, int PERM, int LN>
__global__ __launch_bounds__(256) void gemm_k(
    const float* __restrict__ A, int lda,
    const float* __restrict__ W, int ldw,
    const float* __restrict__ bias,
    const float* res,
    float* C, int ldc,
    int K,
    const float* __restrict__ stats,
    const float* __restrict__ lng, const float* __restrict__ lnb)
{
    __shared__ float As[16][68];
    __shared__ float Ws[16][68];
    __shared__ float ms[64], rss[64];
    const int row0 = blockIdx.y * 64;
    const int col0 = blockIdx.x * 64;
    const int tid = threadIdx.x;
    if (LN) {
        if (tid < 64) {
            ms[tid]  = stats[(row0 + tid) * 2];
            rss[tid] = stats[(row0 + tid) * 2 + 1];
        }
        __syncthreads();
    }
    const int tm = (tid >> 4) << 2;
    const int tn = (tid & 15) << 2;
    float acc[4][4] = {};
    for (int k0 = 0; k0 < K; k0 += 16) {
#pragma unroll
        for (int i = 0; i < 4; i++) {
            int idx = i * 256 + tid;
            int r = idx >> 4, kk = idx & 15;
            float v = A[(size_t)(row0 + r) * lda + (k0 + kk)];
            if (LN) v = (v - ms[r]) * rss[r] * lng[k0 + kk] + lnb[k0 + kk];
            As[kk][r] = v;
        }
#pragma unroll
        for (int i = 0; i < 4; i++) {
            int idx = i * 256 + tid;
            int kk = idx >> 6, c = idx & 63;
            Ws[kk][c] = W[(size_t)(k0 + kk) * ldw + (col0 + c)];
        }
        __syncthreads();
#pragma unroll
        for (int kk = 0; kk < 16; kk++) {
            float4 a4 = *reinterpret_cast<const float4*>(&As[kk][tm]);
            float4 b4 = *reinterpret_cast<const float4*>(&Ws[kk][tn]);
            const float a[4] = {a4.x, a4.y, a4.z, a4.w};
            const float b[4] = {b4.x, b4.y, b4.z, b4.w};
#pragma unroll
            for (int i = 0; i < 4; i++)
#pragma unroll
                for (int j = 0; j < 4; j++)
                    acc[i][j] += a[i] * b[j];
        }
        __syncthreads();
    }
#pragma unroll
    for (int i = 0; i < 4; i++) {
        int r = row0 + tm + i;
#pragma unroll
        for (int j = 0; j < 4; j++) {
            int c = col0 + tn + j;
            float v = acc[i][j];
            if (bias) v += bias[c];
            if (ACT == 1) v = gelu_exact(v);
            if (res) v += res[(size_t)r * ldc + c];
            if (PERM) {
                int bb = r & 63, ss = r >> 6;
                C[((size_t)bb * 512 + ss) * ldc + c] = v;
            } else {
                C[(size_t)r * ldc + c] = v;
            }
        }
    }
}

// ---------------------------------------------------------------- pool (+LN)
// grid (64 batches, 8 dim-groups), 256 thr = 4 s-groups x 64 dims.
__global__ __launch_bounds__(256) void pool_ln_k(
    const float* __restrict__ h, const float* __restrict__ st,
    const float* __restrict__ gf, const float* __restrict__ bf,
    float* __restrict__ pooled)
{
    __shared__ float part[4][64];
    const int b = blockIdx.x;
    const int dg = blockIdx.y << 6;
    const int sg = threadIdx.x >> 6, d = threadIdx.x & 63;
    const float g = gf[dg + d], bb = bf[dg + d];
    float acc = 0.f;
    for (int s = sg; s < 512; s += 4) {
        int r = s * 64 + b;
        float m = st[r * 2], rs = st[r * 2 + 1];
        acc += (h[(size_t)r * 512 + dg + d] - m) * rs * g + bb;
    }
    part[sg][d] = acc;
    __syncthreads();
    if (sg == 0)
        pooled[b * 512 + dg + d] =
            (part[0][d] + part[1][d] + part[2][d] + part[3][d]) * (1.f / 512.f);
}

// ---------------------------------------------------------------- host side
static void run_layer2(const float* const* p, int l,
                       float* h, unsigned short* hn_bf,
                       unsigned short* qkv, int chunk_rows,
                       unsigned short* f1c, int cw,
                       unsigned short* wqkv_t, unsigned short* wo_t,
                       unsigned short* f1_t, unsigned short* f2_t,
                       bool do_wt,
                       hipStream_t stream)
{
    const float* g1  = p[0] + l * 512;
    const float* b1  = p[1] + l * 512;
    const float* wq  = p[2] + (size_t)l * 262144;
    const float* wk  = p[3] + (size_t)l * 262144;
    const float* wv  = p[4] + (size_t)l * 262144;
    const float* wo  = p[5] + (size_t)l * 262144;
    const float* wob = p[6] + l * 512;
    const float* g2  = p[7] + l * 512;
    const float* b2  = p[8] + l * 512;
    const float* f1W = p[9] + (size_t)l * 1048576;
    const float* f1b = p[10] + l * 2048;
    const float* f2W = p[11] + (size_t)l * 1048576;
    const float* f2b = p[12] + l * 512;

    if (do_wt) {   // fallback path: per-layer transpose into small buffers
        WTDesc d0 = {wq,  wqkv_t,          512,  512};
        WTDesc d1 = {wk,  wqkv_t + 262144, 512,  512};
        WTDesc d2 = {wv,  wqkv_t + 524288, 512,  512};
        WTDesc d3 = {wo,  wo_t,            512,  512};
        WTDesc d4 = {f1W, f1_t,            512,  2048};
        WTDesc d5 = {f2W, f2_t,            2048, 512};
        wtcast6_k<<<dim3(64, 64, 6), 256, 0, stream>>>(d0, d1, d2, d3, d4, d5);
    }

    // ---- attention block ----
    cast_ln_k<<<8192, 256, 0, stream>>>(h, g1, b1, hn_bf);
    for (int r0 = 0; r0 < 32768; r0 += chunk_rows) {
        mgemm128_k<0, 1, 0, 0><<<dim3(chunk_rows / 128, 12), 256, 0, stream>>>(
            hn_bf + (size_t)r0 * 512, 512, wqkv_t, 512, nullptr,
            nullptr, nullptr, qkv, 1536, 512);
        attn3_k<<<(chunk_rows / 64) * 8, 256, 0, stream>>>(
            qkv, hn_bf + (size_t)r0 * 512);           // ctx overwrites hn_bf
    }
    mgemm128_k<0, 0, 1, 1><<<dim3(256, 4), 256, 0, stream>>>(
        hn_bf, 512, wo_t, 512, wob, h, h, nullptr, 512, 512);

    // ---- FFN block ----
    cast_ln_k<<<8192, 256, 0, stream>>>(h, g2, b2, hn_bf);
    for (int c0 = 0; c0 < 2048; c0 += cw) {
        mgemm128_k<1, 1, 0, 1><<<dim3(256, cw / 128), 256, 0, stream>>>(
            hn_bf, 512, f1_t + (size_t)c0 * 512, 512, f1b + c0,
            nullptr, nullptr, f1c, cw, 512);
        if (c0 == 0)
            mgemm128_k<0, 0, 1, 1><<<dim3(256, 4), 256, 0, stream>>>(
                f1c, cw, f2_t + c0, 2048, f2b, h, h, nullptr, 512, cw);
        else
            mgemm128_k<0, 0, 1, 0><<<dim3(256, 4), 256, 0, stream>>>(
                f1c, cw, f2_t + c0, 2048, nullptr, h, h, nullptr, 512, cw);
    }
}

extern "C" void kernel_launch(void* const* d_in, const int* in_sizes, int n_in,
                              void* d_out, int out_size, void* d_ws, size_t ws_size,
                              hipStream_t stream)
{
    const float* x       = (const float*)d_in[0];
    const float* enc_inW = (const float*)d_in[1];
    const float* enc_inb = (const float*)d_in[2];
    const float* mu_W    = (const float*)d_in[3];
    const float* mu_b    = (const float*)d_in[4];
    const float* lv_W    = (const float*)d_in[5];
    const float* lv_b    = (const float*)d_in[6];
    const float* dec_inW = (const float*)d_in[7];
    const float* dec_inb = (const float*)d_in[8];
    const float* out_W   = (const float*)d_in[9];
    const float* out_b   = (const float*)d_in[10];
    const float* const* ep = (const float* const*)(d_in + 11);
    const float* const* dp = (const float* const*)(d_in + 26);

    float* fout   = (float*)d_out;             // recon (64,512,64)
    float* mu_out = fout + 2097152;            // (64,128)
    float* lv_out = mu_out + 8192;             // (64,128)

    const size_t SZ = (size_t)32768 * 512;
    size_t off = 0;
    char* base = (char*)d_ws;
    auto take = [&](size_t bytes) -> char* {
        char* pp = base + off;
        off = (off + bytes + 255) & ~(size_t)255;
        return pp;
    };
    float*          h      = (float*)take(SZ * 4);            // 64 MB
    unsigned short* hn_bf  = (unsigned short*)take(SZ * 2);   // 32 MB
    unsigned short* wqkv_t = (unsigned short*)take(1536 * 512 * 2);
    unsigned short* wo_t   = (unsigned short*)take(512 * 512 * 2);
    unsigned short* f1_t   = (unsigned short*)take(2048 * 512 * 2);
    unsigned short* f2_t   = (unsigned short*)take(512 * 2048 * 2);
    float*          stats  = (float*)take(65536 * 4);
    float*          pooled = (float*)take(131072);
    float*          zemb   = (float*)take(131072);
    float*          pe     = (float*)take(512 * 512 * 4);     // 1 MB

    unsigned short* qkv; unsigned short* f1c;
    int chunk_rows, cw;
    size_t rem = (ws_size > off) ? (ws_size - off) : 0;
    const size_t F1_FULL  = (size_t)32768 * 2048 * 2;   // 128 MB
    const size_t QKV_FULL = (size_t)32768 * 1536 * 2;   // 96 MB
    if (rem >= F1_FULL + 512) {                 // single-dispatch FFN tier
        unsigned short* share = (unsigned short*)take(F1_FULL);
        qkv = share; f1c = share; chunk_rows = 32768; cw = 2048;
    } else if (rem >= QKV_FULL + 512) {
        unsigned short* share = (unsigned short*)take(QKV_FULL);
        qkv = share; f1c = share; chunk_rows = 32768; cw = 512;
    } else if (rem >= (size_t)32768 * 512 * 2 + 512) {
        unsigned short* share = (unsigned short*)take((size_t)32768 * 512 * 2);
        qkv = share; f1c = share; chunk_rows = 8192; cw = 512;
    } else {
        qkv = (unsigned short*)take((size_t)4096 * 1536 * 2);
        chunk_rows = 4096;
        f1c = (unsigned short*)fout; cw = 128;  // d_out recon = 8MB scratch
    }

    // batched 2-layer weight buffer (12 MB) if it fits; else per-layer path
    unsigned short* wt2 = nullptr;
    {
        size_t rem2 = (ws_size > off) ? (ws_size - off) : 0;
        const size_t WT2 = (size_t)2 * 3145728 * 2;     // 12 MB
        if (rem2 >= WT2 + 512) wt2 = (unsigned short*)take(WT2);
    }
    const bool batched = (wt2 != nullptr);

    const int M = 32768;

    pe_k<<<512, 256, 0, stream>>>(pe);

    // ---------------- encoder ----------------
    embed_gemm_k<<<dim3(8, 512), 256, 0, stream>>>(x, enc_inW, enc_inb, pe, h);
    if (batched) {
        WTB wb;
        for (int l = 0; l < 2; l++) {
            wb.src[l * 6 + 0] = ep[2] + (size_t)l * 262144;    // wq
            wb.src[l * 6 + 1] = ep[3] + (size_t)l * 262144;    // wk
            wb.src[l * 6 + 2] = ep[4] + (size_t)l * 262144;    // wv
            wb.src[l * 6 + 3] = ep[5] + (size_t)l * 262144;    // wo
            wb.src[l * 6 + 4] = ep[9] + (size_t)l * 1048576;   // f1W
            wb.src[l * 6 + 5] = ep[11] + (size_t)l * 1048576;  // f2W
        }
        wtcast_b_k<<<6144, 256, 0, stream>>>(wb, wt2);
        for (int l = 0; l < 2; l++) {
            unsigned short* wl = wt2 + (size_t)l * 3145728;
            run_layer2(ep, l, h, hn_bf, qkv, chunk_rows, f1c, cw,
                       wl, wl + 786432, wl + 1048576, wl + 2097152,
                       false, stream);
        }
    } else {
        for (int l = 0; l < 2; l++)
            run_layer2(ep, l, h, hn_bf, qkv, chunk_rows, f1c, cw,
                       wqkv_t, wo_t, f1_t, f2_t, true, stream);
    }

    // ---------------- latent ----------------
    stats_k<<<8192, 256, 0, stream>>>(h, stats);
    pool_ln_k<<<dim3(64, 8), 256, 0, stream>>>(h, stats, ep[13], ep[14], pooled);
    gemm_k<0, 0, 0><<<dim3(2, 1), 256, 0, stream>>>(pooled, 512, mu_W, 128, mu_b,
                                                    nullptr, mu_out, 128, 512,
                                                    nullptr, nullptr, nullptr);
    gemm_k<0, 0, 0><<<dim3(2, 1), 256, 0, stream>>>(pooled, 512, lv_W, 128, lv_b,
                                                    nullptr, lv_out, 128, 512,
                                                    nullptr, nullptr, nullptr);
    gemm_k<0, 0, 0><<<dim3(8, 1), 256, 0, stream>>>(mu_out, 128, dec_inW, 512, dec_inb,
                                                    nullptr, zemb, 512, 128,
                                                    nullptr, nullptr, nullptr);
    dec_embed_k<<<16384, 256, 0, stream>>>(zemb, pe, h);

    // ---------------- decoder ----------------
    if (batched) {
        WTB wb;
        for (int l = 0; l < 2; l++) {
            wb.src[l * 6 + 0] = dp[2] + (size_t)l * 262144;
            wb.src[l * 6 + 1] = dp[3] + (size_t)l * 262144;
            wb.src[l * 6 + 2] = dp[4] + (size_t)l * 262144;
            wb.src[l * 6 + 3] = dp[5] + (size_t)l * 262144;
            wb.src[l * 6 + 4] = dp[9] + (size_t)l * 1048576;
            wb.src[l * 6 + 5] = dp[11] + (size_t)l * 1048576;
        }
        wtcast_b_k<<<6144, 256, 0, stream>>>(wb, wt2);
        for (int l = 0; l < 2; l++) {
            unsigned short* wl = wt2 + (size_t)l * 3145728;
            run_layer2(dp, l, h, hn_bf, qkv, chunk_rows, f1c, cw,
                       wl, wl + 786432, wl + 1048576, wl + 2097152,
                       false, stream);
        }
    } else {
        for (int l = 0; l < 2; l++)
            run_layer2(dp, l, h, hn_bf, qkv, chunk_rows, f1c, cw,
                       wqkv_t, wo_t, f1_t, f2_t, true, stream);
    }

    // final LN + out-proj, stored as (B,S,INP)
    stats_k<<<8192, 256, 0, stream>>>(h, stats);
    gemm_k<0, 1, 1><<<dim3(1, M / 64), 256, 0, stream>>>(
        h, 512, out_W, 64, out_b, nullptr, fout, 64, 512, stats, dp[13], dp[14]);
}

// Round 9
// 1920.782 us; speedup vs baseline: 1.0660x; 1.0660x over previous
//
#include <hip/hip_runtime.h>
#include <math.h>

// TransformerVAE forward — round 13.
// Round-12 base (batched wtcast, wave-per-row LN, pool fix) with the GEMM
// replaced by a FAITHFUL m201-style 256x256 8-phase kernel (mgemm256p_k):
//   - 8 waves (2Mx4N), BK=64, 2 K-tiles/iteration, 2 LDS buffers (128 KiB).
//   - Phase = {quadrant frag ds-reads; stage ONE half-tile (2 GLL); barrier;
//     lgkmcnt(0)+sched_barrier; setprio(1); 16 MFMA; setprio(0); barrier}.
//   - Stage slots (hazard-proven): t1-Alo@p1, t1-Ahi@p2, kt2-Blo@p3,
//     kt2-Bhi@p4, kt2-Alo@p5, kt2-Ahi@p6, kt3-Blo@p7, kt3-Bhi@p8.
//     Every staged region's last reads drained >=1 phase earlier (each
//     phase's reads drain at its own lgkmcnt(0) before its end barrier).
//   - vmcnt(4) ONLY at phases 4 and 8 (2 half-tiles in flight; never 0
//     mid-loop).  Gate@p4 proves t1 fully landed before p5 reads it;
//     gate@p8 proves kt2 landed before next-iter p1.
//   - Session-verified XOR swizzle (elem col ^= (row&7)<<3, inverse on GLL
//     source) and swapped C/D map kept verbatim.
// Rationale: rounds 5-12 tried 7 GEMM structures, all 455-540 TF at
// MfmaUtil ~22% — none was the true fine-interleaved 8-phase schedule,
// which is the documented prerequisite for the 1563 TF regime.
// B=64, S=512, INP=64, D=512, H=8, dk=64, L=2, DFF=2048, LAT=128, topk=6.

#define SQRT_D 22.62741699796952f
#define PE_C   0.017988946039015984f   // ln(10000)/512

typedef short frag8 __attribute__((ext_vector_type(8)));   // 8 bf16
typedef float accf4 __attribute__((ext_vector_type(4)));   // 4 fp32 acc

#define GLL16(g, l) __builtin_amdgcn_global_load_lds( \
    (const __attribute__((address_space(1))) void*)(g), \
    (__attribute__((address_space(3))) void*)(l), 16, 0, 0)

__device__ __forceinline__ float bf2f(unsigned short u) {
    union { unsigned i; float f; } v; v.i = ((unsigned)u) << 16; return v.f;
}
__device__ __forceinline__ unsigned short f2bf(float f) {   // RNE
    union { float f; unsigned i; } v; v.f = f;
    unsigned r = v.i + 0x7fff + ((v.i >> 16) & 1);
    return (unsigned short)(r >> 16);
}
__device__ __forceinline__ float pe_val(int s, int d) {
    float div = expf(-(float)(d & ~1) * PE_C);
    float ang = (float)s * div;
    return (d & 1) ? cosf(ang) : sinf(ang);
}
__device__ __forceinline__ float gelu_exact(float x) {
    return 0.5f * x * (1.0f + erff(x * 0.7071067811865476f));
}
// Abramowitz-Stegun 7.1.26 erf, |err| < 1.5e-7 (≪ bf16 output quantum).
__device__ __forceinline__ float gelu_fast(float x) {
    float xs = x * 0.7071067811865476f;
    float ax = fabsf(xs);
    float t  = 1.0f / (1.0f + 0.3275911f * ax);
    float p  = t * (0.254829592f + t * (-0.284496736f + t * (1.421413741f +
               t * (-1.453152027f + t * 1.061405429f))));
    float er = 1.0f - p * __expf(-ax * ax);
    er = (xs < 0.0f) ? -er : er;
    return 0.5f * x * (1.0f + er);
}

__device__ __forceinline__ void phase_bar() {
    __builtin_amdgcn_sched_barrier(0);
    __builtin_amdgcn_s_barrier();
    __builtin_amdgcn_sched_barrier(0);
}

// ---------------------------------------------------------------- PE table
__global__ __launch_bounds__(256) void pe_k(float* __restrict__ pe)
{
    const int s = blockIdx.x;
    const int d = threadIdx.x;
    pe[s * 512 + d]       = pe_val(s, d);
    pe[s * 512 + d + 256] = pe_val(s, d + 256);
}

// ---------------------------------------------------------------- embed (enc)
__global__ __launch_bounds__(256) void embed_gemm_k(
    const float* __restrict__ x, const float* __restrict__ W,
    const float* __restrict__ bias, const float* __restrict__ pe,
    float* __restrict__ h)
{
    __shared__ float As[64][68];   // As[kk][b]
    __shared__ float Ws[64][68];   // Ws[kk][c]
    const int s = blockIdx.y;
    const int col0 = blockIdx.x * 64;
    const int tid = threadIdx.x;
#pragma unroll
    for (int i = 0; i < 16; i++) {
        int idx = i * 256 + tid;
        int r = idx >> 6, kk = idx & 63;
        As[kk][r] = x[((size_t)r * 512 + s) * 64 + kk];       // r = b
        Ws[r][kk] = W[(size_t)r * 512 + col0 + kk];           // r = k, kk = c
    }
    __syncthreads();
    const int tm = (tid >> 4) << 2;
    const int tn = (tid & 15) << 2;
    float acc[4][4] = {};
#pragma unroll 8
    for (int kk = 0; kk < 64; kk++) {
        float4 a4 = *reinterpret_cast<const float4*>(&As[kk][tm]);
        float4 b4 = *reinterpret_cast<const float4*>(&Ws[kk][tn]);
        const float a[4] = {a4.x, a4.y, a4.z, a4.w};
        const float b[4] = {b4.x, b4.y, b4.z, b4.w};
#pragma unroll
        for (int i = 0; i < 4; i++)
#pragma unroll
            for (int j = 0; j < 4; j++)
                acc[i][j] += a[i] * b[j];
    }
    const int c = col0 + tn;
    float4 bi = *reinterpret_cast<const float4*>(&bias[c]);
    float4 pp = *reinterpret_cast<const float4*>(&pe[s * 512 + c]);
#pragma unroll
    for (int i = 0; i < 4; i++) {
        size_t row = ((size_t)s * 64 + tm + i) * 512;
        float4 o;
        o.x = (acc[i][0] + bi.x) * SQRT_D + pp.x;
        o.y = (acc[i][1] + bi.y) * SQRT_D + pp.y;
        o.z = (acc[i][2] + bi.z) * SQRT_D + pp.z;
        o.w = (acc[i][3] + bi.w) * SQRT_D + pp.w;
        *reinterpret_cast<float4*>(&h[row + c]) = o;
    }
}

// ---------------------------------------------------------------- embed (dec)
__global__ __launch_bounds__(256) void dec_embed_k(
    const float* __restrict__ zemb, const float* __restrict__ pe,
    float* __restrict__ h)
{
    const int i4 = (blockIdx.x * 256 + threadIdx.x) * 4;   // grid 16384
    const int d = i4 & 511;
    const int t = i4 >> 9;
    const int s = t >> 6, b = t & 63;
    float4 z = *reinterpret_cast<const float4*>(&zemb[b * 512 + d]);
    float4 p = *reinterpret_cast<const float4*>(&pe[s * 512 + d]);
    float4 o;
    o.x = z.x * SQRT_D + p.x;
    o.y = z.y * SQRT_D + p.y;
    o.z = z.z * SQRT_D + p.z;
    o.w = z.w * SQRT_D + p.w;
    *reinterpret_cast<float4*>(&h[i4]) = o;
}

// ------------------------------------------------- LN stats (wave-per-row)
__global__ __launch_bounds__(256) void stats_k(
    const float* __restrict__ x, float* __restrict__ st)
{
    const int wave = threadIdx.x >> 6, lane = threadIdx.x & 63;
    const int row = blockIdx.x * 4 + wave;
    const float* xr = x + (size_t)row * 512 + lane * 8;
    float4 a = *reinterpret_cast<const float4*>(xr);
    float4 c = *reinterpret_cast<const float4*>(xr + 4);
    float s = a.x + a.y + a.z + a.w + c.x + c.y + c.z + c.w;
#pragma unroll
    for (int off = 32; off > 0; off >>= 1) s += __shfl_xor(s, off, 64);
    const float m = s * (1.f / 512.f);
    float d0 = a.x - m, d1 = a.y - m, d2 = a.z - m, d3 = a.w - m;
    float d4 = c.x - m, d5 = c.y - m, d6 = c.z - m, d7 = c.w - m;
    float s2 = d0*d0 + d1*d1 + d2*d2 + d3*d3 + d4*d4 + d5*d5 + d6*d6 + d7*d7;
#pragma unroll
    for (int off = 32; off > 0; off >>= 1) s2 += __shfl_xor(s2, off, 64);
    if (lane == 0) {
        st[row * 2]     = m;
        st[row * 2 + 1] = rsqrtf(s2 * (1.f / 512.f) + 1e-5f);
    }
}

// ------------------------------------------------- LN->bf16 (wave-per-row)
__global__ __launch_bounds__(256) void cast_ln_k(
    const float* __restrict__ x, const float* __restrict__ g,
    const float* __restrict__ b, unsigned short* __restrict__ y)
{
    const int wave = threadIdx.x >> 6, lane = threadIdx.x & 63;
    const int row = blockIdx.x * 4 + wave;
    const float* xr = x + (size_t)row * 512 + lane * 8;
    float4 a = *reinterpret_cast<const float4*>(xr);
    float4 c = *reinterpret_cast<const float4*>(xr + 4);
    float s = a.x + a.y + a.z + a.w + c.x + c.y + c.z + c.w;
#pragma unroll
    for (int off = 32; off > 0; off >>= 1) s += __shfl_xor(s, off, 64);
    const float m = s * (1.f / 512.f);
    float d0 = a.x - m, d1 = a.y - m, d2 = a.z - m, d3 = a.w - m;
    float d4 = c.x - m, d5 = c.y - m, d6 = c.z - m, d7 = c.w - m;
    float s2 = d0*d0 + d1*d1 + d2*d2 + d3*d3 + d4*d4 + d5*d5 + d6*d6 + d7*d7;
#pragma unroll
    for (int off = 32; off > 0; off >>= 1) s2 += __shfl_xor(s2, off, 64);
    const float rstd = rsqrtf(s2 * (1.f / 512.f) + 1e-5f);
    float4 g0 = *reinterpret_cast<const float4*>(&g[lane * 8]);
    float4 g1 = *reinterpret_cast<const float4*>(&g[lane * 8 + 4]);
    float4 b0 = *reinterpret_cast<const float4*>(&b[lane * 8]);
    float4 b1 = *reinterpret_cast<const float4*>(&b[lane * 8 + 4]);
    frag8 o;
    o[0] = (short)f2bf(d0 * rstd * g0.x + b0.x);
    o[1] = (short)f2bf(d1 * rstd * g0.y + b0.y);
    o[2] = (short)f2bf(d2 * rstd * g0.z + b0.z);
    o[3] = (short)f2bf(d3 * rstd * g0.w + b0.w);
    o[4] = (short)f2bf(d4 * rstd * g1.x + b1.x);
    o[5] = (short)f2bf(d5 * rstd * g1.y + b1.y);
    o[6] = (short)f2bf(d6 * rstd * g1.z + b1.z);
    o[7] = (short)f2bf(d7 * rstd * g1.w + b1.w);
    *reinterpret_cast<frag8*>(&y[(size_t)row * 512 + lane * 8]) = o;
}

// ------------------------------------------------------- weight transpose+cast
struct WTDesc { const float* src; unsigned short* dst; int Kd; int Nd; };

__global__ __launch_bounds__(256) void wtcast6_k(
    WTDesc d0, WTDesc d1, WTDesc d2, WTDesc d3, WTDesc d4, WTDesc d5)
{
    WTDesc d;
    switch (blockIdx.z) {
        case 0: d = d0; break; case 1: d = d1; break; case 2: d = d2; break;
        case 3: d = d3; break; case 4: d = d4; break; default: d = d5; break;
    }
    const int n0 = blockIdx.x * 32, k0 = blockIdx.y * 32;
    if (n0 >= d.Nd || k0 >= d.Kd) return;
    __shared__ float t[32][33];
    const int tx = threadIdx.x & 31, ty = threadIdx.x >> 5;   // ty 0..7
#pragma unroll
    for (int i = 0; i < 32; i += 8)
        t[ty + i][tx] = d.src[(size_t)(k0 + ty + i) * d.Nd + (n0 + tx)];
    __syncthreads();
#pragma unroll
    for (int i = 0; i < 32; i += 8)
        d.dst[(size_t)(n0 + ty + i) * d.Kd + (k0 + tx)] = f2bf(t[tx][ty + i]);
}

// ------------------------------------ batched 2-layer weight transpose+cast
struct WTB { const float* src[12]; };   // [layer*6 + {wq,wk,wv,wo,f1,f2}]

__global__ __launch_bounds__(256) void wtcast_b_k(
    WTB w, unsigned short* __restrict__ dstbase)
{
    const int id = blockIdx.x;
    const int layer = id / 3072, r = id - layer * 3072;
    int di, t;
    if (r < 1024)      { di = r >> 8; t = r & 255; }
    else if (r < 2048) { di = 4; t = r - 1024; }
    else               { di = 5; t = r - 2048; }
    const float* src = w.src[layer * 6 + di];
    int Kd, Nd, n0, k0; size_t doff;
    if (di == 4)      { Kd = 512;  Nd = 2048; n0 = (t & 63) * 32; k0 = (t >> 6) * 32; doff = 1048576; }
    else if (di == 5) { Kd = 2048; Nd = 512;  n0 = (t & 15) * 32; k0 = (t >> 4) * 32; doff = 2097152; }
    else              { Kd = 512;  Nd = 512;  n0 = (t & 15) * 32; k0 = (t >> 4) * 32; doff = (size_t)di * 262144; }
    unsigned short* dst = dstbase + (size_t)layer * 3145728 + doff;
    __shared__ float tt[32][33];
    const int tx = threadIdx.x & 31, ty = threadIdx.x >> 5;
#pragma unroll
    for (int i = 0; i < 32; i += 8)
        tt[ty + i][tx] = src[(size_t)(k0 + ty + i) * Nd + (n0 + tx)];
    __syncthreads();
#pragma unroll
    for (int i = 0; i < 32; i += 8)
        dst[(size_t)(n0 + ty + i) * Kd + (k0 + tx)] = f2bf(tt[tx][ty + i]);
}

// --------------------------------- MFMA GEMM 256x256, 8-phase (m201 port)
// C[M,N] = A[M,K](bf16) @ Bt[N,K](bf16)^T (+bias)(gelu?)(+fp32 res).
template<int ACT, int OUTBF, int RES, int BIAS>
__global__ __launch_bounds__(512, 1) void mgemm256p_k(
    const unsigned short* __restrict__ A, int lda,
    const unsigned short* __restrict__ Bt, int ldb,
    const float* __restrict__ bias,
    const float* res, float* Cf, unsigned short* Cb, int ldc, int K)
{
    __shared__ unsigned short sm[65536];   // 128 KiB: 2 buf x (A 32KB + B 32KB)
    const int tid = threadIdx.x;
    const int wave = tid >> 6, lane = tid & 63;

    int bx = blockIdx.x, by = blockIdx.y;
    if (gridDim.x == 128) {   // XCD swizzle: 16 row-tiles/XCD, 8-tile halves
        const int gy = gridDim.y;
        const int id = blockIdx.y * 128 + blockIdx.x;
        const int xcd = id & 7;
        const int q = id >> 3;            // [0, 16*gy)
        const int hb = q / (gy * 8);      // 0 or 1
        const int rr = q - hb * gy * 8;   // [0, 8*gy)
        bx = (xcd << 4) + (hb << 3) + (rr & 7);
        by = rr >> 3;
    }
    const int row0 = bx * 256, col0 = by * 256;

    const int wr = wave >> 2, wc = wave & 3;           // 2 x 4 wave grid
    const int wrbase = wr * 128, wcbase = wc * 64;
    const int frow = lane & 15;
    const int fcol = (lane >> 4) * 8;
    const int fxorE = (lane & 7) << 3;
    const int kx0 = fcol ^ fxorE;
    const int kx1 = (32 + fcol) ^ fxorE;
    int aoff[8], boff[4];
#pragma unroll
    for (int m = 0; m < 8; m++) aoff[m] = (wrbase + m * 16 + frow) * 64;
#pragma unroll
    for (int n = 0; n < 4; n++) boff[n] = 16384 + (wcbase + n * 16 + frow) * 64;

    // stage geometry: 512 thr cover 64 rows x 128B per GLL round (2/half)
    const int srow = tid >> 3;                         // 0..63
    const int scol = ((tid & 7) ^ (srow & 7)) * 8;     // inverse swizzle

    auto stA = [&](int kt, int half) {
        const int bb = (kt & 1) << 15;
        const int r = half * 128 + srow;
        GLL16(A + (size_t)(row0 + r) * lda + (kt << 6) + scol, &sm[bb + r * 64]);
        GLL16(A + (size_t)(row0 + r + 64) * lda + (kt << 6) + scol, &sm[bb + (r + 64) * 64]);
    };
    auto stB = [&](int kt, int half) {
        const int bb = ((kt & 1) << 15) + 16384;
        const int r = half * 128 + srow;
        GLL16(Bt + (size_t)(col0 + r) * ldb + (kt << 6) + scol, &sm[bb + r * 64]);
        GLL16(Bt + (size_t)(col0 + r + 64) * ldb + (kt << 6) + scol, &sm[bb + (r + 64) * 64]);
    };

    const int NT = K >> 6;                // even, >= 8 for all call sites
    accf4 acc[8][4] = {};
    frag8 fA[4][2], fB[4][2];

#define LDS8(off) (*(const frag8*)&sm[(off)])
#define MFMA_Q(MB, N0, AROW)                                                    \
    __builtin_amdgcn_s_setprio(1);                                              \
    _Pragma("unroll")                                                           \
    for (int m = 0; m < 4; m++)                                                 \
        _Pragma("unroll")                                                       \
        for (int n = 0; n < 2; n++)                                             \
            _Pragma("unroll")                                                   \
            for (int ks = 0; ks < 2; ks++)                                      \
                acc[(AROW) + m][(N0) + n] =                                     \
                    __builtin_amdgcn_mfma_f32_16x16x32_bf16(                    \
                        fB[(N0) + n][ks], fA[m][ks],                            \
                        acc[(AROW) + m][(N0) + n], 0, 0, 0);                    \
    __builtin_amdgcn_s_setprio(0);

    // ---- prologue: kt0 fully staged + kt1's B halves (12 loads);
    //      vmcnt(4) -> kt0 landed, kt1-B (4 loads) stays in flight.
    stA(0, 0); stA(0, 1); stB(0, 0); stB(0, 1);
    stB(1, 0); stB(1, 1);
    asm volatile("s_waitcnt vmcnt(4)" ::: "memory");
    phase_bar();

    for (int t0 = 0; t0 < NT; t0 += 2) {
        const int t1 = t0 + 1;
        const int kt2 = t0 + 2, kt3 = t0 + 3;
        const bool p2 = kt2 < NT, p3 = kt3 < NT;
        const int tb0 = 0, tb1 = 32768;

        // ---- phase 1: reads q0 of t0 (A mi0-3, B nj0-1; 12 ds); stage t1-Alo
#pragma unroll
        for (int m = 0; m < 4; m++) { fA[m][0] = LDS8(tb0 + aoff[m] + kx0); fA[m][1] = LDS8(tb0 + aoff[m] + kx1); }
#pragma unroll
        for (int n = 0; n < 2; n++) { fB[n][0] = LDS8(tb0 + boff[n] + kx0); fB[n][1] = LDS8(tb0 + boff[n] + kx1); }
        stA(t1, 0);
        asm volatile("s_waitcnt lgkmcnt(8)" ::: "memory");
        phase_bar();
        asm volatile("s_waitcnt lgkmcnt(0)" ::: "memory");
        __builtin_amdgcn_sched_barrier(0);
        MFMA_Q(0, 0, 0)
        phase_bar();

        // ---- phase 2: reads B nj2-3; stage t1-Ahi; MFMA mi0-3 x nj2-3
#pragma unroll
        for (int n = 2; n < 4; n++) { fB[n][0] = LDS8(tb0 + boff[n] + kx0); fB[n][1] = LDS8(tb0 + boff[n] + kx1); }
        stA(t1, 1);
        phase_bar();
        asm volatile("s_waitcnt lgkmcnt(0)" ::: "memory");
        __builtin_amdgcn_sched_barrier(0);
        MFMA_Q(0, 2, 0)
        phase_bar();

        // ---- phase 3: reads A mi4-7; stage kt2-Blo; MFMA mi4-7 x nj0-1
#pragma unroll
        for (int m = 0; m < 4; m++) { fA[m][0] = LDS8(tb0 + aoff[4 + m] + kx0); fA[m][1] = LDS8(tb0 + aoff[4 + m] + kx1); }
        if (p2) stB(kt2, 0);
        phase_bar();
        asm volatile("s_waitcnt lgkmcnt(0)" ::: "memory");
        __builtin_amdgcn_sched_barrier(0);
        MFMA_Q(0, 0, 4)
        phase_bar();

        // ---- phase 4: no reads; stage kt2-Bhi; MFMA mi4-7 x nj2-3; GATE
        if (p2) stB(kt2, 1);
        MFMA_Q(0, 2, 4)
        if (p2) asm volatile("s_waitcnt vmcnt(4)" ::: "memory");
        else    asm volatile("s_waitcnt vmcnt(0)" ::: "memory");
        phase_bar();

        // ---- phase 5: reads q0 of t1; stage kt2-Alo
#pragma unroll
        for (int m = 0; m < 4; m++) { fA[m][0] = LDS8(tb1 + aoff[m] + kx0); fA[m][1] = LDS8(tb1 + aoff[m] + kx1); }
#pragma unroll
        for (int n = 0; n < 2; n++) { fB[n][0] = LDS8(tb1 + boff[n] + kx0); fB[n][1] = LDS8(tb1 + boff[n] + kx1); }
        if (p2) stA(kt2, 0);
        asm volatile("s_waitcnt lgkmcnt(8)" ::: "memory");
        phase_bar();
        asm volatile("s_waitcnt lgkmcnt(0)" ::: "memory");
        __builtin_amdgcn_sched_barrier(0);
        MFMA_Q(0, 0, 0)
        phase_bar();

        // ---- phase 6: reads B nj2-3 of t1; stage kt2-Ahi
#pragma unroll
        for (int n = 2; n < 4; n++) { fB[n][0] = LDS8(tb1 + boff[n] + kx0); fB[n][1] = LDS8(tb1 + boff[n] + kx1); }
        if (p2) stA(kt2, 1);
        phase_bar();
        asm volatile("s_waitcnt lgkmcnt(0)" ::: "memory");
        __builtin_amdgcn_sched_barrier(0);
        MFMA_Q(0, 2, 0)
        phase_bar();

        // ---- phase 7: reads A mi4-7 of t1; stage kt3-Blo
#pragma unroll
        for (int m = 0; m < 4; m++) { fA[m][0] = LDS8(tb1 + aoff[4 + m] + kx0); fA[m][1] = LDS8(tb1 + aoff[4 + m] + kx1); }
        if (p3) stB(kt3, 0);
        phase_bar();
        asm volatile("s_waitcnt lgkmcnt(0)" ::: "memory");
        __builtin_amdgcn_sched_barrier(0);
        MFMA_Q(0, 0, 4)
        phase_bar();

        // ---- phase 8: no reads; stage kt3-Bhi; GATE
        if (p3) stB(kt3, 1);
        MFMA_Q(0, 2, 4)
        if (p3) asm volatile("s_waitcnt vmcnt(4)" ::: "memory");
        else    asm volatile("s_waitcnt vmcnt(0)" ::: "memory");
        phase_bar();
    }
#undef MFMA_Q
#undef LDS8

    // ---- epilogue (swapped C/D map: row = lane&15, col = (lane>>4)*4 + reg)
    const int lrow = lane & 15;
    const int lcol = (lane >> 4) * 4;
#pragma unroll
    for (int mi = 0; mi < 8; mi++) {
        const int r = row0 + wrbase + mi * 16 + lrow;
#pragma unroll
        for (int nj = 0; nj < 4; nj++) {
            const int c = col0 + wcbase + nj * 16 + lcol;
            float4 v = make_float4(acc[mi][nj][0], acc[mi][nj][1],
                                   acc[mi][nj][2], acc[mi][nj][3]);
            if (BIAS) {
                float4 bi = *reinterpret_cast<const float4*>(&bias[c]);
                v.x += bi.x; v.y += bi.y; v.z += bi.z; v.w += bi.w;
            }
            if (ACT) {
                v.x = gelu_fast(v.x); v.y = gelu_fast(v.y);
                v.z = gelu_fast(v.z); v.w = gelu_fast(v.w);
            }
            if (RES) {
                float4 rr = *reinterpret_cast<const float4*>(&res[(size_t)r * ldc + c]);
                v.x += rr.x; v.y += rr.y; v.z += rr.z; v.w += rr.w;
            }
            if (OUTBF) {
                ushort4 o;
                o.x = f2bf(v.x); o.y = f2bf(v.y); o.z = f2bf(v.z); o.w = f2bf(v.w);
                *reinterpret_cast<ushort4*>(&Cb[(size_t)r * ldc + c]) = o;
            } else {
                *reinterpret_cast<float4*>(&Cf[(size_t)r * ldc + c]) = v;
            }
        }
    }
}

// ---------------------- MFMA GEMM 128x128 (fallback tier, round-11 proven)
template<int ACT, int OUTBF, int RES, int BIAS>
__global__ __launch_bounds__(256, 2) void mgemm128_k(
    const unsigned short* __restrict__ A, int lda,
    const unsigned short* __restrict__ Bt, int ldb,
    const float* __restrict__ bias,
    const float* res, float* Cf, unsigned short* Cb, int ldc, int K)
{
    __shared__ unsigned short sm[32768];
    const int tid = threadIdx.x;
    const int wave = tid >> 6, lane = tid & 63;
    const int row0 = blockIdx.x * 128;
    const int col0 = blockIdx.y * 128;
    const int wr = wave >> 1, wc = wave & 1;
    const int wrbase = wr * 64, wcbase = wc * 64;
    const int frow = lane & 15;
    const int fcol = (lane >> 4) * 8;
    const int fxorE = (lane & 7) << 3;
    const int ccol = ((lane & 7) ^ (lane >> 3)) * 8;
    const int NT = K >> 6;

    auto stageA = [&](int buf, int k0t) {
#pragma unroll
        for (int i = 0; i < 4; i++) {
            int chunk = wave * 4 + i;
            GLL16(A + (size_t)(row0 + chunk * 8 + (lane >> 3)) * lda + k0t + ccol,
                  &sm[buf * 16384 + chunk * 512]);
        }
    };
    auto stageB = [&](int buf, int k0t) {
#pragma unroll
        for (int i = 0; i < 4; i++) {
            int chunk = wave * 4 + i;
            GLL16(Bt + (size_t)(col0 + chunk * 8 + (lane >> 3)) * ldb + k0t + ccol,
                  &sm[buf * 16384 + 8192 + chunk * 512]);
        }
    };

    accf4 acc[4][4] = {};
    frag8 af0[4], af1[4], bfr[4][2];
    stageA(0, 0); stageB(0, 0);
    if (NT > 1) { stageA(1, 64); stageB(1, 64); }
    if (NT > 1) asm volatile("s_waitcnt vmcnt(8)" ::: "memory");
    else        asm volatile("s_waitcnt vmcnt(0)" ::: "memory");
    phase_bar();

    for (int t = 0; t < NT; ++t) {
        const int ab = (t & 1) * 16384;
        const int bb = ab + 8192;
        const bool pf = (t + 2) < NT;
        const int kpf = (t + 2) << 6;
#pragma unroll
        for (int mi = 0; mi < 4; mi++)
            af0[mi] = *(const frag8*)&sm[ab + (wrbase + mi * 16 + frow) * 64 + (fcol ^ fxorE)];
#pragma unroll
        for (int nj = 0; nj < 4; nj++)
#pragma unroll
            for (int ks = 0; ks < 2; ks++)
                bfr[nj][ks] = *(const frag8*)&sm[bb + (wcbase + nj * 16 + frow) * 64 + ((ks * 32 + fcol) ^ fxorE)];
        phase_bar();
        __builtin_amdgcn_s_setprio(1);
#pragma unroll
        for (int mi = 0; mi < 4; mi++)
#pragma unroll
            for (int nj = 0; nj < 4; nj++)
                acc[mi][nj] = __builtin_amdgcn_mfma_f32_16x16x32_bf16(
                    bfr[nj][0], af0[mi], acc[mi][nj], 0, 0, 0);
        __builtin_amdgcn_s_setprio(0);
        phase_bar();
#pragma unroll
        for (int mi = 0; mi < 4; mi++)
            af1[mi] = *(const frag8*)&sm[ab + (wrbase + mi * 16 + frow) * 64 + ((32 + fcol) ^ fxorE)];
        if (pf) stageB(t & 1, kpf);
        phase_bar();
        __builtin_amdgcn_s_setprio(1);
#pragma unroll
        for (int mi = 0; mi < 4; mi++)
#pragma unroll
            for (int nj = 0; nj < 4; nj++)
                acc[mi][nj] = __builtin_amdgcn_mfma_f32_16x16x32_bf16(
                    bfr[nj][1], af1[mi], acc[mi][nj], 0, 0, 0);
        __builtin_amdgcn_s_setprio(0);
        if (pf) stageA(t & 1, kpf);
        if (pf) asm volatile("s_waitcnt vmcnt(8)" ::: "memory");
        else    asm volatile("s_waitcnt vmcnt(0)" ::: "memory");
        phase_bar();
    }

    const int lrow = lane & 15;
    const int lcol = (lane >> 4) * 4;
#pragma unroll
    for (int mi = 0; mi < 4; mi++) {
        const int r = row0 + wrbase + mi * 16 + lrow;
#pragma unroll
        for (int nj = 0; nj < 4; nj++) {
            const int c = col0 + wcbase + nj * 16 + lcol;
            float4 v = make_float4(acc[mi][nj][0], acc[mi][nj][1],
                                   acc[mi][nj][2], acc[mi][nj][3]);
            if (BIAS) {
                float4 bi = *reinterpret_cast<const float4*>(&bias[c]);
                v.x += bi.x; v.y += bi.y; v.z += bi.z; v.w += bi.w;
            }
            if (ACT) {
                v.x = gelu_fast(v.x); v.y = gelu_fast(v.y);
                v.z = gelu_fast(v.z); v.w = gelu_fast(v.w);
            }
            if (RES) {
                float4 rr = *reinterpret_cast<const float4*>(&res[(size_t)r * ldc + c]);
                v.x += rr.x; v.y += rr.y; v.z += rr.z; v.w += rr.w;
            }
            if (OUTBF) {
                ushort4 o;
                o.x = f2bf(v.x); o.y = f2bf(v.y); o.z = f2bf(v.z); o.w = f2bf(v.w);
                *reinterpret_cast<ushort4*>(&Cb[(size_t)r * ldc + c]) = o;
            } else {
                *reinterpret_cast<float4*>(&Cf[(size_t)r * ldc + c]) = v;
            }
        }
    }
}

// ---------------------------------------------------------------- attention
__global__ __launch_bounds__(256) void attn3_k(
    const unsigned short* __restrict__ qkv, unsigned short* __restrict__ ctx)
{
    __shared__ unsigned short QL[4096];
    __shared__ unsigned short KL[4096];
    __shared__ unsigned short VT[4096];
    __shared__ float ScT[64][68];
    __shared__ float dsums[64][4];
    __shared__ float rds[64];
    const int blk = blockIdx.x;
    const int sl = blk >> 3, hh = blk & 7;
    const int tid = threadIdx.x;
    const int wave = tid >> 6, lane = tid & 63;
    const size_t qbase = (size_t)sl * 64 * 1536 + (size_t)hh * 64;

    {
        const int r = tid >> 2;
        const int dg = (tid & 3) << 4;
        const int x = (r & 7) << 3;
        const unsigned short* gp = qkv + qbase + (size_t)r * 1536 + dg;
        frag8 q0 = *(const frag8*)(gp);
        frag8 q1 = *(const frag8*)(gp + 8);
        frag8 k0 = *(const frag8*)(gp + 512);
        frag8 k1 = *(const frag8*)(gp + 520);
        frag8 v0 = *(const frag8*)(gp + 1024);
        frag8 v1 = *(const frag8*)(gp + 1032);
        *(frag8*)&QL[r * 64 + (dg ^ x)]       = q0;
        *(frag8*)&QL[r * 64 + ((dg + 8) ^ x)] = q1;
        *(frag8*)&KL[r * 64 + (dg ^ x)]       = k0;
        *(frag8*)&KL[r * 64 + ((dg + 8) ^ x)] = k1;
#pragma unroll
        for (int i = 0; i < 16; i++) {
            int ii = (i + r) & 15;
            int j = dg + ii;
            unsigned short e = (unsigned short)(ii < 8 ? v0[ii] : v1[ii - 8]);
            VT[j * 64 + (r ^ ((j & 7) << 3))] = e;
        }
    }
    __syncthreads();

    const int frow = lane & 15;
    const int fcol8 = (lane >> 4) * 8;
    const int fx = (lane & 7) << 3;

    {   // QK^T
        const int c0 = wave * 16;
        accf4 sacc[4] = {};
#pragma unroll
        for (int ks = 0; ks < 2; ks++) {
            frag8 kf = *(const frag8*)&KL[(c0 + frow) * 64 + ((ks * 32 + fcol8) ^ fx)];
#pragma unroll
            for (int rt = 0; rt < 4; rt++) {
                frag8 qf = *(const frag8*)&QL[(rt * 16 + frow) * 64 + ((ks * 32 + fcol8) ^ fx)];
                sacc[rt] = __builtin_amdgcn_mfma_f32_16x16x32_bf16(
                    qf, kf, sacc[rt], 0, 0, 0);
            }
        }
        const int cc = c0 + frow;
        const int rb = (lane >> 4) * 4;
#pragma unroll
        for (int rt = 0; rt < 4; rt++) {
            float4 s4;
            s4.x = sacc[rt][0] * 0.125f; s4.y = sacc[rt][1] * 0.125f;
            s4.z = sacc[rt][2] * 0.125f; s4.w = sacc[rt][3] * 0.125f;
            *(float4*)&ScT[cc][rt * 16 + rb] = s4;
        }
    }
    __syncthreads();

    const int row = tid & 63, seg = tid >> 6;
    float* candp = (float*)&KL[0];
    {
        float top[6];
#pragma unroll
        for (int i = 0; i < 6; i++) top[i] = -3.4e38f;
#pragma unroll
        for (int c = seg * 16; c < seg * 16 + 16; c++) {
            float vv = ScT[c][row];
            if (vv > top[5]) {
                top[5] = vv;
#pragma unroll
                for (int i = 5; i > 0; i--)
                    if (top[i] > top[i - 1]) { float t = top[i]; top[i] = top[i - 1]; top[i - 1] = t; }
            }
        }
#pragma unroll
        for (int i = 0; i < 6; i++) candp[row * 24 + seg * 6 + i] = top[i];
    }
    __syncthreads();
    if (seg == 0) {
        float t6[6];
#pragma unroll
        for (int i = 0; i < 6; i++) t6[i] = -3.4e38f;
#pragma unroll
        for (int j = 0; j < 24; j++) {
            float vv = candp[row * 24 + j];
            if (vv > t6[5]) {
                t6[5] = vv;
#pragma unroll
                for (int i = 5; i > 0; i--)
                    if (t6[i] > t6[i - 1]) { float t = t6[i]; t6[i] = t6[i - 1]; t6[i - 1] = t; }
            }
        }
        ScT[row][64] = t6[5];
        ScT[row][65] = t6[0];
    }
    __syncthreads();
    {
        const float thresh = ScT[row][64], mx = ScT[row][65];
        const int xr = (row & 7) << 3;
        float dsum = 0.f;
#pragma unroll
        for (int c = seg * 16; c < seg * 16 + 16; c++) {
            float vv = ScT[c][row];
            float w = (vv >= thresh) ? expf(vv - mx) : 0.f;
            unsigned short wb = f2bf(w);
            dsum += bf2f(wb);
            QL[row * 64 + (c ^ xr)] = wb;
        }
        dsums[row][seg] = dsum;
    }
    __syncthreads();
    if (tid < 64)
        rds[tid] = 1.f / (dsums[tid][0] + dsums[tid][1] + dsums[tid][2] + dsums[tid][3]);
    __syncthreads();

    {   // PV
        const int r0 = wave * 16;
        accf4 pacc[4] = {};
#pragma unroll
        for (int ks = 0; ks < 2; ks++) {
            frag8 pf = *(const frag8*)&QL[(r0 + frow) * 64 + ((ks * 32 + fcol8) ^ fx)];
#pragma unroll
            for (int jt = 0; jt < 4; jt++) {
                frag8 vf = *(const frag8*)&VT[(jt * 16 + frow) * 64 + ((ks * 32 + fcol8) ^ fx)];
                pacc[jt] = __builtin_amdgcn_mfma_f32_16x16x32_bf16(
                    vf, pf, pacc[jt], 0, 0, 0);
            }
        }
        const int rr = r0 + frow;
        const int jb = (lane >> 4) * 4;
        const float sc = rds[rr];
#pragma unroll
        for (int jt = 0; jt < 4; jt++) {
            ushort4 o;
            o.x = f2bf(pacc[jt][0] * sc); o.y = f2bf(pacc[jt][1] * sc);
            o.z = f2bf(pacc[jt][2] * sc); o.w = f2bf(pacc[jt][3] * sc);
            *reinterpret_cast<ushort4*>(
                &ctx[(size_t)(sl * 64 + rr) * 512 + hh * 64 + jt * 16 + jb]) = o;
        }
    }
}

// ---------------------------------------------------------- fp32 GEMM (small)
template<int ACT, int PERM, int LN>
__global__ __launch_bounds__(256) void gemm_k(
    const float* __restrict__ A, int lda,
    const float* __restrict__ W, int ldw,
    const float* __restrict__ bias,
    const float* res,
    float* C, int ldc,
    int K,
    const float* __restrict__ stats,
    const float* __restrict__ lng, const float* __restrict__ lnb)
{
    __shared__ float As[16][68];
    __shared__ float Ws[16][68];
    __shared__ float ms[64], rss[64];
    const int row0 = blockIdx.y * 64;
    const int col0 = blockIdx.x * 64;
    const int tid = threadIdx.x;
    if (LN) {
        if (tid < 64) {
            ms[tid]  = stats[(row0 + tid) * 2];
            rss[tid] = stats[(row0 + tid) * 2 + 1];
        }
        __syncthreads();
    }
    const int tm = (tid >> 4) << 2;
    const int tn = (tid & 15) << 2;
    float acc[4][4] = {};
    for (int k0 = 0; k0 < K; k0 += 16) {
#pragma unroll
        for (int i = 0; i < 4; i++) {
            int idx = i * 256 + tid;
            int r = idx >> 4, kk = idx & 15;
            float v = A[(size_t)(row0 + r) * lda + (k0 + kk)];
            if (LN) v = (v - ms[r]) * rss[r] * lng[k0 + kk] + lnb[k0 + kk];
            As[kk][r] = v;
        }
#pragma unroll
        for (int i = 0; i < 4; i++) {
            int idx = i * 256 + tid;
            int kk = idx >> 6, c = idx & 63;
            Ws[kk][c] = W[(size_t)(k0 + kk) * ldw + (col0 + c)];
        }
        __syncthreads();
#pragma unroll
        for (int kk = 0; kk < 16; kk++) {
            float4 a4 = *reinterpret_cast<const float4*>(&As[kk][tm]);
            float4 b4 = *reinterpret_cast<const float4*>(&Ws[kk][tn]);
            const float a[4] = {a4.x, a4.y, a4.z, a4.w};
            const float b[4] = {b4.x, b4.y, b4.z, b4.w};
#pragma unroll
            for (int i = 0; i < 4; i++)
#pragma unroll
                for (int j = 0; j < 4; j++)
                    acc[i][j] += a[i] * b[j];
        }
        __syncthreads();
    }
#pragma unroll
    for (int i = 0; i < 4; i++) {
        int r = row0 + tm + i;
#pragma unroll
        for (int j = 0; j < 4; j++) {
            int c = col0 + tn + j;
            float v = acc[i][j];
            if (bias) v += bias[c];
            if (ACT == 1) v = gelu_exact(v);
            if (res) v += res[(size_t)r * ldc + c];
            if (PERM) {
                int bb = r & 63, ss = r >> 6;
                C[((size_t)bb * 512 + ss) * ldc + c] = v;
            } else {
                C[(size_t)r * ldc + c] = v;
            }
        }
    }
}

// ---------------------------------------------------------------- pool (+LN)
__global__ __launch_bounds__(256) void pool_ln_k(
    const float* __restrict__ h, const float* __restrict__ st,
    const float* __restrict__ gf, const float* __restrict__ bf,
    float* __restrict__ pooled)
{
    __shared__ float part[4][64];
    const int b = blockIdx.x;
    const int dg = blockIdx.y << 6;
    const int sg = threadIdx.x >> 6, d = threadIdx.x & 63;
    const float g = gf[dg + d], bb = bf[dg + d];
    float acc = 0.f;
    for (int s = sg; s < 512; s += 4) {
        int r = s * 64 + b;
        float m = st[r * 2], rs = st[r * 2 + 1];
        acc += (h[(size_t)r * 512 + dg + d] - m) * rs * g + bb;
    }
    part[sg][d] = acc;
    __syncthreads();
    if (sg == 0)
        pooled[b * 512 + dg + d] =
            (part[0][d] + part[1][d] + part[2][d] + part[3][d]) * (1.f / 512.f);
}

// ---------------------------------------------------------------- host side
static void run_layer2(const float* const* p, int l,
                       float* h, unsigned short* hn_bf,
                       unsigned short* qkv, int chunk_rows,
                       unsigned short* f1c, int cw,
                       unsigned short* wqkv_t, unsigned short* wo_t,
                       unsigned short* f1_t, unsigned short* f2_t,
                       bool do_wt,
                       hipStream_t stream)
{
    const float* g1  = p[0] + l * 512;
    const float* b1  = p[1] + l * 512;
    const float* wq  = p[2] + (size_t)l * 262144;
    const float* wk  = p[3] + (size_t)l * 262144;
    const float* wv  = p[4] + (size_t)l * 262144;
    const float* wo  = p[5] + (size_t)l * 262144;
    const float* wob = p[6] + l * 512;
    const float* g2  = p[7] + l * 512;
    const float* b2  = p[8] + l * 512;
    const float* f1W = p[9] + (size_t)l * 1048576;
    const float* f1b = p[10] + l * 2048;
    const float* f2W = p[11] + (size_t)l * 1048576;
    const float* f2b = p[12] + l * 512;

    if (do_wt) {
        WTDesc d0 = {wq,  wqkv_t,          512,  512};
        WTDesc d1 = {wk,  wqkv_t + 262144, 512,  512};
        WTDesc d2 = {wv,  wqkv_t + 524288, 512,  512};
        WTDesc d3 = {wo,  wo_t,            512,  512};
        WTDesc d4 = {f1W, f1_t,            512,  2048};
        WTDesc d5 = {f2W, f2_t,            2048, 512};
        wtcast6_k<<<dim3(64, 64, 6), 256, 0, stream>>>(d0, d1, d2, d3, d4, d5);
    }

    // ---- attention block ----
    cast_ln_k<<<8192, 256, 0, stream>>>(h, g1, b1, hn_bf);
    for (int r0 = 0; r0 < 32768; r0 += chunk_rows) {
        mgemm256p_k<0, 1, 0, 0><<<dim3(chunk_rows / 256, 6), 512, 0, stream>>>(
            hn_bf + (size_t)r0 * 512, 512, wqkv_t, 512, nullptr,
            nullptr, nullptr, qkv, 1536, 512);
        attn3_k<<<(chunk_rows / 64) * 8, 256, 0, stream>>>(
            qkv, hn_bf + (size_t)r0 * 512);           // ctx overwrites hn_bf
    }
    mgemm256p_k<0, 0, 1, 1><<<dim3(128, 2), 512, 0, stream>>>(
        hn_bf, 512, wo_t, 512, wob, h, h, nullptr, 512, 512);

    // ---- FFN block ----
    cast_ln_k<<<8192, 256, 0, stream>>>(h, g2, b2, hn_bf);
    if (cw >= 256) {
        for (int c0 = 0; c0 < 2048; c0 += cw) {
            mgemm256p_k<1, 1, 0, 1><<<dim3(128, cw / 256), 512, 0, stream>>>(
                hn_bf, 512, f1_t + (size_t)c0 * 512, 512, f1b + c0,
                nullptr, nullptr, f1c, cw, 512);
            if (c0 == 0)
                mgemm256p_k<0, 0, 1, 1><<<dim3(128, 2), 512, 0, stream>>>(
                    f1c, cw, f2_t + c0, 2048, f2b, h, h, nullptr, 512, cw);
            else
                mgemm256p_k<0, 0, 1, 0><<<dim3(128, 2), 512, 0, stream>>>(
                    f1c, cw, f2_t + c0, 2048, nullptr, h, h, nullptr, 512, cw);
        }
    } else {
        for (int c0 = 0; c0 < 2048; c0 += cw) {
            mgemm128_k<1, 1, 0, 1><<<dim3(256, cw / 128), 256, 0, stream>>>(
                hn_bf, 512, f1_t + (size_t)c0 * 512, 512, f1b + c0,
                nullptr, nullptr, f1c, cw, 512);
            if (c0 == 0)
                mgemm128_k<0, 0, 1, 1><<<dim3(256, 4), 256, 0, stream>>>(
                    f1c, cw, f2_t + c0, 2048, f2b, h, h, nullptr, 512, cw);
            else
                mgemm128_k<0, 0, 1, 0><<<dim3(256, 4), 256, 0, stream>>>(
                    f1c, cw, f2_t + c0, 2048, nullptr, h, h, nullptr, 512, cw);
        }
    }
}

extern "C" void kernel_launch(void* const* d_in, const int* in_sizes, int n_in,
                              void* d_out, int out_size, void* d_ws, size_t ws_size,
                              hipStream_t stream)
{
    const float* x       = (const float*)d_in[0];
    const float* enc_inW = (const float*)d_in[1];
    const float* enc_inb = (const float*)d_in[2];
    const float* mu_W    = (const float*)d_in[3];
    const float* mu_b    = (const float*)d_in[4];
    const float* lv_W    = (const float*)d_in[5];
    const float* lv_b    = (const float*)d_in[6];
    const float* dec_inW = (const float*)d_in[7];
    const float* dec_inb = (const float*)d_in[8];
    const float* out_W   = (const float*)d_in[9];
    const float* out_b   = (const float*)d_in[10];
    const float* const* ep = (const float* const*)(d_in + 11);
    const float* const* dp = (const float* const*)(d_in + 26);

    float* fout   = (float*)d_out;             // recon (64,512,64)
    float* mu_out = fout + 2097152;            // (64,128)
    float* lv_out = mu_out + 8192;             // (64,128)

    const size_t SZ = (size_t)32768 * 512;
    size_t off = 0;
    char* base = (char*)d_ws;
    auto take = [&](size_t bytes) -> char* {
        char* pp = base + off;
        off = (off + bytes + 255) & ~(size_t)255;
        return pp;
    };
    float*          h      = (float*)take(SZ * 4);            // 64 MB
    unsigned short* hn_bf  = (unsigned short*)take(SZ * 2);   // 32 MB
    unsigned short* wqkv_t = (unsigned short*)take(1536 * 512 * 2);
    unsigned short* wo_t   = (unsigned short*)take(512 * 512 * 2);
    unsigned short* f1_t   = (unsigned short*)take(2048 * 512 * 2);
    unsigned short* f2_t   = (unsigned short*)take(512 * 2048 * 2);
    float*          stats  = (float*)take(65536 * 4);
    float*          pooled = (float*)take(131072);
    float*          zemb   = (float*)take(131072);
    float*          pe     = (float*)take(512 * 512 * 4);     // 1 MB

    unsigned short* qkv; unsigned short* f1c;
    int chunk_rows, cw;
    size_t rem = (ws_size > off) ? (ws_size - off) : 0;
    const size_t F1_FULL  = (size_t)32768 * 2048 * 2;   // 128 MB
    const size_t QKV_FULL = (size_t)32768 * 1536 * 2;   // 96 MB
    if (rem >= F1_FULL + 512) {                 // single-dispatch FFN tier
        unsigned short* share = (unsigned short*)take(F1_FULL);
        qkv = share; f1c = share; chunk_rows = 32768; cw = 2048;
    } else if (rem >= QKV_FULL + 512) {
        unsigned short* share = (unsigned short*)take(QKV_FULL);
        qkv = share; f1c = share; chunk_rows = 32768; cw = 512;
    } else if (rem >= (size_t)32768 * 512 * 2 + 512) {
        unsigned short* share = (unsigned short*)take((size_t)32768 * 512 * 2);
        qkv = share; f1c = share; chunk_rows = 8192; cw = 512;
    } else {
        qkv = (unsigned short*)take((size_t)4096 * 1536 * 2);
        chunk_rows = 4096;
        f1c = (unsigned short*)fout; cw = 128;  // d_out recon = 8MB scratch
    }

    // batched 2-layer weight buffer (12 MB) if it fits; else per-layer path
    unsigned short* wt2 = nullptr;
    {
        size_t rem2 = (ws_size > off) ? (ws_size - off) : 0;
        const size_t WT2 = (size_t)2 * 3145728 * 2;     // 12 MB
        if (rem2 >= WT2 + 512) wt2 = (unsigned short*)take(WT2);
    }
    const bool batched = (wt2 != nullptr);

    const int M = 32768;

    pe_k<<<512, 256, 0, stream>>>(pe);

    // ---------------- encoder ----------------
    embed_gemm_k<<<dim3(8, 512), 256, 0, stream>>>(x, enc_inW, enc_inb, pe, h);
    if (batched) {
        WTB wb;
        for (int l = 0; l < 2; l++) {
            wb.src[l * 6 + 0] = ep[2] + (size_t)l * 262144;
            wb.src[l * 6 + 1] = ep[3] + (size_t)l * 262144;
            wb.src[l * 6 + 2] = ep[4] + (size_t)l * 262144;
            wb.src[l * 6 + 3] = ep[5] + (size_t)l * 262144;
            wb.src[l * 6 + 4] = ep[9] + (size_t)l * 1048576;
            wb.src[l * 6 + 5] = ep[11] + (size_t)l * 1048576;
        }
        wtcast_b_k<<<6144, 256, 0, stream>>>(wb, wt2);
        for (int l = 0; l < 2; l++) {
            unsigned short* wl = wt2 + (size_t)l * 3145728;
            run_layer2(ep, l, h, hn_bf, qkv, chunk_rows, f1c, cw,
                       wl, wl + 786432, wl + 1048576, wl + 2097152,
                       false, stream);
        }
    } else {
        for (int l = 0; l < 2; l++)
            run_layer2(ep, l, h, hn_bf, qkv, chunk_rows, f1c, cw,
                       wqkv_t, wo_t, f1_t, f2_t, true, stream);
    }

    // ---------------- latent ----------------
    stats_k<<<8192, 256, 0, stream>>>(h, stats);
    pool_ln_k<<<dim3(64, 8), 256, 0, stream>>>(h, stats, ep[13], ep[14], pooled);
    gemm_k<0, 0, 0><<<dim3(2, 1), 256, 0, stream>>>(pooled, 512, mu_W, 128, mu_b,
                                                    nullptr, mu_out, 128, 512,
                                                    nullptr, nullptr, nullptr);
    gemm_k<0, 0, 0><<<dim3(2, 1), 256, 0, stream>>>(pooled, 512, lv_W, 128, lv_b,
                                                    nullptr, lv_out, 128, 512,
                                                    nullptr, nullptr, nullptr);
    gemm_k<0, 0, 0><<<dim3(8, 1), 256, 0, stream>>>(mu_out, 128, dec_inW, 512, dec_inb,
                                                    nullptr, zemb, 512, 128,
                                                    nullptr, nullptr, nullptr);
    dec_embed_k<<<16384, 256, 0, stream>>>(zemb, pe, h);

    // ---------------- decoder ----------------
    if (batched) {
        WTB wb;
        for (int l = 0; l < 2; l++) {
            wb.src[l * 6 + 0] = dp[2] + (size_t)l * 262144;
            wb.src[l * 6 + 1] = dp[3] + (size_t)l * 262144;
            wb.src[l * 6 + 2] = dp[4] + (size_t)l * 262144;
            wb.src[l * 6 + 3] = dp[5] + (size_t)l * 262144;
            wb.src[l * 6 + 4] = dp[9] + (size_t)l * 1048576;
            wb.src[l * 6 + 5] = dp[11] + (size_t)l * 1048576;
        }
        wtcast_b_k<<<6144, 256, 0, stream>>>(wb, wt2);
        for (int l = 0; l < 2; l++) {
            unsigned short* wl = wt2 + (size_t)l * 3145728;
            run_layer2(dp, l, h, hn_bf, qkv, chunk_rows, f1c, cw,
                       wl, wl + 786432, wl + 1048576, wl + 2097152,
                       false, stream);
        }
    } else {
        for (int l = 0; l < 2; l++)
            run_layer2(dp, l, h, hn_bf, qkv, chunk_rows, f1c, cw,
                       wqkv_t, wo_t, f1_t, f2_t, true, stream);
    }

    // final LN + out-proj, stored as (B,S,INP)
    stats_k<<<8192, 256, 0, stream>>>(h, stats);
    gemm_k<0, 1, 1><<<dim3(1, M / 64), 256, 0, stream>>>(
        h, 512, out_W, 64, out_b, nullptr, fout, 64, 512, stats, dp[13], dp[14]);
}